// Round 4
// baseline (619.466 us; speedup 1.0000x reference)
//
#include <hip/hip_runtime.h>
#include <hip/hip_bf16.h>

// Match numpy: no FMA contraction anywhere that feeds the Jacobi argmax.
#pragma clang fp contract(off)

#define N 4096
#define CIN 64
#define COUT 64
#define ITERS 10

typedef unsigned long long u64;

// Fused: deg[r] += 1, A[r,c] += 1 (exact small ints in f32)
__global__ void edges_k(const int* __restrict__ ei, float* __restrict__ deg,
                        float* __restrict__ a, int E) {
    int e = blockIdx.x * 256 + threadIdx.x;
    if (e < E) {
        int r = ei[e];
        int c = ei[E + e];
        atomicAdd(&deg[r], 1.0f);
        atomicAdd(&a[(size_t)r * N + c], 1.0f);
    }
}

__global__ void dinv_k(const float* __restrict__ deg, float* __restrict__ dinv) {
    int i = blockIdx.x * 256 + threadIdx.x;
    if (i < N) {
        float d = deg[i];
        dinv[i] = (d > 0.0f) ? (1.0f / sqrtf(d)) : 0.0f;  // correctly-rounded div+sqrt = numpy
    }
}

__global__ void init_y_k(const float* __restrict__ x, float* __restrict__ y) {
    int idx = blockIdx.x * 256 + threadIdx.x;
    if (idx < N * CIN) y[idx] = x[idx];
}

// Transpose weights to [i][o] layout for coalesced lane-o access in spectral_k.
__global__ void prepw_k(const float* __restrict__ hh, const float* __restrict__ cw,
                        const float* __restrict__ rw, const float* __restrict__ iw,
                        float2* __restrict__ hcT, float4* __restrict__ rwT,
                        float4* __restrict__ iwT) {
    int idx = blockIdx.x * 256 + threadIdx.x;   // 4096 = i*64+o
    int i = idx >> 6, o = idx & 63;
    int src = o * 64 + i;
    hcT[idx] = make_float2(hh[src], cw[src]);
    rwT[idx] = make_float4(rw[src * 4 + 0], rw[src * 4 + 1], rw[src * 4 + 2], rw[src * 4 + 3]);
    iwT[idx] = make_float4(iw[src * 4 + 0], iw[src * 4 + 1], iw[src * 4 + 2], iw[src * 4 + 3]);
}

// Shared finisher: block-reduce packed (val,~idx), atomicMax into slot, last block
// computes rotation params (exact reference op order), rotates y (U^T x), resets ctl.
__device__ __forceinline__ void amax_finish(
        float bv, unsigned bi, float* a, float* __restrict__ y,
        u64* slot, unsigned* counter, unsigned nblocks,
        int* rotk, int* rotl, float* rotc, float* rotsv, int it) {
    __shared__ u64 sp[256];
    int t = threadIdx.x;
    sp[t] = ((u64)__float_as_uint(bv) << 32) | (u64)(unsigned)(~bi);
    __syncthreads();
    for (int off = 128; off > 0; off >>= 1) {
        if (t < off) { u64 o = sp[t + off]; if (o > sp[t]) sp[t] = o; }
        __syncthreads();
    }
    __shared__ int slast;
    if (t == 0) {
        atomicMax(slot, sp[0]);
        __threadfence();
        unsigned prev = atomicAdd(counter, 1u);
        slast = (prev == nblocks - 1) ? 1 : 0;
    }
    __syncthreads();
    if (!slast) return;
    __shared__ int skk, sll;
    __shared__ float scc, sss;
    if (t == 0) {
        __threadfence();
        u64 p = atomicMax(slot, 0ull);          // coherent read of the max
        unsigned idx = ~(unsigned)(p & 0xFFFFFFFFull);
        int k = (int)(idx >> 12);
        int l = (int)(idx & 4095u);
        // atomic reads: safe vs same-kernel writes from other XCDs (formL case)
        float akl = atomicAdd(&a[(size_t)k * N + l], 0.0f);
        float akk = atomicAdd(&a[(size_t)k * N + k], 0.0f);
        float all = atomicAdd(&a[(size_t)l * N + l], 0.0f);
        float aDiff = all - akk;
        float akl_safe = (akl == 0.0f) ? 1.0f : akl;
        float aDiff_safe = (aDiff == 0.0f) ? 1.0f : aDiff;
        float phi = aDiff / (2.0f * akl_safe);
        float t2 = 1.0f / (fabsf(phi) + sqrtf(phi * phi + 1.0f));
        t2 = (phi < 0.0f) ? -t2 : t2;
        float t1 = akl / aDiff_safe;
        float tt = (fabsf(akl) < fabsf(aDiff) * 1e-36f) ? t1 : t2;
        float cv = 1.0f / sqrtf(tt * tt + 1.0f);
        float sval = tt * cv;
        rotk[it] = k; rotl[it] = l; rotc[it] = cv; rotsv[it] = sval;
        skk = k; sll = l; scc = cv; sss = sval;
        atomicExch(slot, 0ull);                 // reset for next iteration
        atomicExch(counter, 0u);
    }
    __syncthreads();
    int k = skk, l = sll;
    float c = scc, s = sss;
    if (t < CIN) {                              // incremental U^T x (G^T on rows k,l)
        float yk = y[k * CIN + t], yl = y[l * CIN + t];
        y[k * CIN + t] = c * yk - s * yl;
        y[l * CIN + t] = s * yk + c * yl;
    }
}

// a[i,j] = (i==j?1:0) - (dinv[i]*A_ij)*dinv[j], fused with the it=0 argmax scan.
__global__ void __launch_bounds__(256) formL_amax_k(
        float* __restrict__ a, const float* __restrict__ dinv, float* __restrict__ y,
        u64* slot, unsigned* counter,
        int* rotk, int* rotl, float* rotc, float* rotsv) {
    unsigned base = blockIdx.x * 16384u;
    float bv = -1.0f; unsigned bi = 0u;
    for (int s = 0; s < 16; ++s) {
        unsigned idx0 = base + (unsigned)s * 1024u + (unsigned)threadIdx.x * 4u;
        unsigned i = idx0 >> 12, j0 = idx0 & 4095u;
        float di = dinv[i];
        float4 v4 = *reinterpret_cast<const float4*>(a + idx0);
        float4 dj = *reinterpret_cast<const float4*>(dinv + j0);
        float4 r;
        r.x = ((j0 + 0 == i) ? 1.0f : 0.0f) - ((di * v4.x) * dj.x);
        r.y = ((j0 + 1 == i) ? 1.0f : 0.0f) - ((di * v4.y) * dj.y);
        r.z = ((j0 + 2 == i) ? 1.0f : 0.0f) - ((di * v4.z) * dj.z);
        r.w = ((j0 + 3 == i) ? 1.0f : 0.0f) - ((di * v4.w) * dj.w);
        *reinterpret_cast<float4*>(a + idx0) = r;
        float c0 = (j0 + 0 > i) ? fabsf(r.x) : 0.0f;
        float c1 = (j0 + 1 > i) ? fabsf(r.y) : 0.0f;
        float c2 = (j0 + 2 > i) ? fabsf(r.z) : 0.0f;
        float c3 = (j0 + 3 > i) ? fabsf(r.w) : 0.0f;
        if (c0 > bv) { bv = c0; bi = idx0 + 0; }
        if (c1 > bv) { bv = c1; bi = idx0 + 1; }
        if (c2 > bv) { bv = c2; bi = idx0 + 2; }
        if (c3 > bv) { bv = c3; bi = idx0 + 3; }
    }
    amax_finish(bv, bi, a, y, slot, counter, gridDim.x, rotk, rotl, rotc, rotsv, 0);
}

// Full scan argmax of where(j>i, |a|, 0) with fused finisher for iteration `it`.
__global__ void __launch_bounds__(256) amax_k(
        float* __restrict__ a, float* __restrict__ y,
        u64* slot, unsigned* counter,
        int* rotk, int* rotl, float* rotc, float* rotsv, int it) {
    unsigned base = blockIdx.x * 16384u;
    float bv = -1.0f; unsigned bi = 0u;
    for (int s = 0; s < 16; ++s) {
        unsigned idx0 = base + (unsigned)s * 1024u + (unsigned)threadIdx.x * 4u;
        unsigned i = idx0 >> 12, j0 = idx0 & 4095u;
        float4 v4 = *reinterpret_cast<const float4*>(a + idx0);
        float c0 = (j0 + 0 > i) ? fabsf(v4.x) : 0.0f;
        float c1 = (j0 + 1 > i) ? fabsf(v4.y) : 0.0f;
        float c2 = (j0 + 2 > i) ? fabsf(v4.z) : 0.0f;
        float c3 = (j0 + 3 > i) ? fabsf(v4.w) : 0.0f;
        if (c0 > bv) { bv = c0; bi = idx0 + 0; }
        if (c1 > bv) { bv = c1; bi = idx0 + 1; }
        if (c2 > bv) { bv = c2; bi = idx0 + 2; }
        if (c3 > bv) { bv = c3; bi = idx0 + 3; }
    }
    amax_finish(bv, bi, a, y, slot, counter, gridDim.x, rotk, rotl, rotc, rotsv, it);
}

// Fully-parallel rotation apply. Writes are disjoint:
//   i!=k,l : (i,k),(i,l) col update (originals; row update never touches rows!=k,l)
//   j!=k,l : (k,j),(l,j) row update (originals; col update never touches cols!=k,l)
//   2x2 block {k,l}x{k,l}: one thread, exact reference op order.
__global__ void __launch_bounds__(256) update_k(
        float* __restrict__ a,
        const int* __restrict__ rotk, const int* __restrict__ rotl,
        const float* __restrict__ rotc, const float* __restrict__ rotsv, int it) {
    int k = rotk[it], l = rotl[it];
    float c = rotc[it], s = rotsv[it];
    int idx = blockIdx.x * 256 + threadIdx.x;   // 0..4095
    if (idx == k) {
        float akk = a[(size_t)k * N + k], akl = a[(size_t)k * N + l];
        float alk = a[(size_t)l * N + k], all = a[(size_t)l * N + l];
        float a1kk = c * akk - s * akl;   // col update, i=k
        float a1kl = s * akk + c * akl;
        float a1lk = c * alk - s * all;   // col update, i=l
        float a1ll = s * alk + c * all;
        float a2kk = c * a1kk - s * a1lk; // row update, diag
        float a2ll = s * a1kl + c * a1ll;
        a[(size_t)k * N + k] = a2kk;
        a[(size_t)l * N + l] = a2ll;
        a[(size_t)k * N + l] = 0.0f;      // zeros last (handles k==l degenerate)
        a[(size_t)l * N + k] = 0.0f;
    } else if (idx != l) {
        int i = idx;
        float ck = a[(size_t)i * N + k], cl = a[(size_t)i * N + l];
        a[(size_t)i * N + k] = c * ck - s * cl;
        a[(size_t)i * N + l] = s * ck + c * cl;
        int j = idx;
        float rk = a[(size_t)k * N + j], rl = a[(size_t)l * N + j];
        a[(size_t)k * N + j] = c * rk - s * rl;
        a[(size_t)l * N + j] = s * rk + c * rl;
    }
}

// z[n,o] = sum_i g(o,i,n) * y[n,i]; transcendental-free:
// cos(2*atan(1/hw)) = (hw^2-1)/(hw^2+1), sin = 2hw/(hw^2+1); Chebyshev for j=2..4.
__global__ void __launch_bounds__(1024) spectral_k(
        const float* __restrict__ a, const float* __restrict__ y,
        const float2* __restrict__ hcT, const float4* __restrict__ rwT,
        const float4* __restrict__ iwT, float* __restrict__ z) {
    int o = threadIdx.x & 63;
    int nl = threadIdx.x >> 6;          // 0..15
    int n = blockIdx.x * 16 + nl;
    __shared__ float saux[16][CIN];
    saux[nl][o] = y[n * CIN + o];
    __syncthreads();
    float wn = a[(size_t)n * 4097u];    // diagonal
    const float C2 = -0.41614683654714241f;   // cos(2.0)
    const float S2 = 0.90929742682568170f;    // sin(2.0)
    float acc = 0.0f;
    for (int i = 0; i < CIN; ++i) {
        float2 hc = hcT[i * 64 + o];
        float hw = hc.x * wn;
        float t2v = hw * hw;
        float inv = 1.0f / (t2v + 1.0f);
        float c1 = (t2v - 1.0f) * inv;
        float s1 = (2.0f * hw) * inv;
        if (!(hw > 1e-5f)) { c1 = C2; s1 = S2; }
        float4 rwv = rwT[i * 64 + o];
        float4 iwv = iwT[i * 64 + o];
        float g = hc.y;
        float cj = c1, sj = s1;
        g += rwv.x * cj - iwv.x * sj;
        float cn = cj * c1 - sj * s1; float sn = sj * c1 + cj * s1; cj = cn; sj = sn;
        g += rwv.y * cj - iwv.y * sj;
        cn = cj * c1 - sj * s1; sn = sj * c1 + cj * s1; cj = cn; sj = sn;
        g += rwv.z * cj - iwv.z * sj;
        cn = cj * c1 - sj * s1; sn = sj * c1 + cj * s1; cj = cn; sj = sn;
        g += rwv.w * cj - iwv.w * sj;
        acc += g * saux[nl][i];
    }
    z[(size_t)n * COUT + o] = acc;
}

// output = U @ out.T : apply G_10 ... G_1 to z rows (each thread owns one column).
__global__ void finalrot_k(float* __restrict__ z,
                           const int* __restrict__ rotk, const int* __restrict__ rotl,
                           const float* __restrict__ rotc, const float* __restrict__ rotsv) {
    int col = threadIdx.x;  // 0..63
    for (int i = ITERS - 1; i >= 0; --i) {
        int k = rotk[i], l = rotl[i];
        float c = rotc[i], s = rotsv[i];
        float zk = z[k * COUT + col];
        float zl = z[l * COUT + col];
        z[k * COUT + col] = c * zk + s * zl;   // (G z)[k]
        z[l * COUT + col] = -s * zk + c * zl;  // (G z)[l]
    }
}

__global__ void store_k(const float* __restrict__ z, const float* __restrict__ bias,
                        float* __restrict__ out) {
    int idx = blockIdx.x * 256 + threadIdx.x;
    if (idx < N * COUT) {
        int o = idx & 63;
        out[idx] = z[idx] + bias[o];
    }
}

extern "C" void kernel_launch(void* const* d_in, const int* in_sizes, int n_in,
                              void* d_out, int out_size, void* d_ws, size_t ws_size,
                              hipStream_t stream) {
    const float* x   = (const float*)d_in[0];
    const int*   ei  = (const int*)d_in[1];
    const float* rw  = (const float*)d_in[2];
    const float* iw  = (const float*)d_in[3];
    const float* hh  = (const float*)d_in[4];
    const float* cw  = (const float*)d_in[5];
    const float* bias= (const float*)d_in[6];
    float* out = (float*)d_out;

    // Workspace carve (~66.3 MB). [a | deg | slot | counter+pad | dinv | y | z | wT | rot]
    float* a    = (float*)d_ws;             // 16777216 f32 (64 MB)
    float* deg  = a + (size_t)N * N;        // 4096
    u64*   slot = (u64*)(deg + N);          // 1 (8B, 16B-aligned)
    unsigned* counter = (unsigned*)(slot + 1); // 1 (+1 pad)
    float* dinv = (float*)(slot + 2);       // 4096 (16B-aligned for float4)
    float* y    = dinv + N;                 // 262144 : U^T x (incrementally rotated)
    float* z    = y + N * CIN;              // 262144 : out.T then U*out.T
    float2* hcT = (float2*)(z + N * COUT);  // 4096 float2
    float4* rwT = (float4*)(hcT + 4096);    // 4096 float4
    float4* iwT = rwT + 4096;               // 4096 float4
    int*   rotk = (int*)(iwT + 4096);       // 16
    int*   rotl = rotk + 16;                // 16
    float* rotc = (float*)(rotl + 16);      // 16
    float* rotsv= rotc + 16;                // 16

    int E = in_sizes[1] / 2;                // 200000 (row half of edge_index)

    // zero a + deg + slot + counter in one memset (contiguous)
    hipMemsetAsync(a, 0, (size_t)N * N * 4 + N * 4 + 16, stream);

    int eb = (E + 255) / 256;
    edges_k<<<eb, 256, 0, stream>>>(ei, deg, a, E);
    dinv_k<<<16, 256, 0, stream>>>(deg, dinv);
    prepw_k<<<16, 256, 0, stream>>>(hh, cw, rw, iw, hcT, rwT, iwT);
    init_y_k<<<1024, 256, 0, stream>>>(x, y);

    formL_amax_k<<<1024, 256, 0, stream>>>(a, dinv, y, slot, counter,
                                           rotk, rotl, rotc, rotsv);
    update_k<<<16, 256, 0, stream>>>(a, rotk, rotl, rotc, rotsv, 0);
    for (int it = 1; it < ITERS; ++it) {
        amax_k<<<1024, 256, 0, stream>>>(a, y, slot, counter,
                                         rotk, rotl, rotc, rotsv, it);
        update_k<<<16, 256, 0, stream>>>(a, rotk, rotl, rotc, rotsv, it);
    }

    spectral_k<<<N / 16, 1024, 0, stream>>>(a, y, hcT, rwT, iwT, z);
    finalrot_k<<<1, 64, 0, stream>>>(z, rotk, rotl, rotc, rotsv);
    store_k<<<1024, 256, 0, stream>>>(z, bias, out);
}